// Round 6
// baseline (430.272 us; speedup 1.0000x reference)
//
#include <hip/hip_runtime.h>
#include <hip/hip_bf16.h>
#include <cstdint>
#include <type_traits>

// Problem constants (reference: N=8192, D=2048, M=512, E=4, SCALE=1)
#define N_TOK 8192
#define DDIM  2048
#define MDIM  512
#define NEXP  4
#define PADROWS (N_TOK + NEXP * 256)   // expert ranges padded to 256 -> 9216
#define NB   512                       // fused persistent grid (2 blocks/CU)
#define NTHR 256                       // 4 waves

typedef __bf16 bf16x4 __attribute__((ext_vector_type(4)));
typedef __bf16 bf16x8 __attribute__((ext_vector_type(8)));
typedef float  f32x4  __attribute__((ext_vector_type(4)));

// ---------------------------------------------------------------------------
// Device state. g_arrive is a monotonic grid-barrier ticket counter: each
// barrier instance consumes exactly NB consecutive tickets; 2^32 % NB == 0 so
// wraparound preserves generation alignment across graph replays.
// ---------------------------------------------------------------------------
__device__ unsigned g_arrive;                      // zero-init at module load
__device__ int g_blkcnt[NB][NEXP];
__device__ int g_counts[NEXP];
__device__ int g_idx[NEXP * N_TOK];
__device__ __align__(16) __hip_bfloat16 g_Xp[(size_t)DDIM * PADROWS];       // 37.7 MB
__device__ __align__(16) __hip_bfloat16 g_Hp[(size_t)MDIM * PADROWS];       //  9.4 MB
__device__ __align__(16) __hip_bfloat16 g_W1t[(size_t)NEXP * MDIM * DDIM];  //  8.4 MB
__device__ __align__(16) __hip_bfloat16 g_W2t[(size_t)NEXP * DDIM * MDIM];  //  8.4 MB

struct SMem {
    __hip_bfloat16 sA[2][128 * 64];    // 32 KB
    __hip_bfloat16 sB[2][128 * 64];    // 32 KB
    int sTok[128];
};                                      // 66048 B -> 2 blocks/CU

// Grid barrier: release = syncthreads (drains stores to L2) + threadfence
// (L2 writeback, device scope) + ticket; acquire = spin + threadfence (inv).
__device__ __forceinline__ void gsync() {
    __syncthreads();
    if (threadIdx.x == 0) {
        __threadfence();
        unsigned t = atomicAdd(&g_arrive, 1u);            // my ticket (pre-add)
        unsigned target = (t & ~(unsigned)(NB - 1)) + NB; // end of my generation
        while ((int)(atomicAdd(&g_arrive, 0u) - target) < 0)
            __builtin_amdgcn_s_sleep(10);                 // polite poll
        __threadfence();
    }
    __syncthreads();
}

// global -> LDS direct DMA, 16B/lane (wave-uniform LDS base + lane*16).
__device__ __forceinline__ void gl16(const __hip_bfloat16* g, __hip_bfloat16* l) {
    __builtin_amdgcn_global_load_lds(
        (const __attribute__((address_space(1))) void*)g,
        (__attribute__((address_space(3))) void*)l,
        16, 0, 0);
}

template <int N>
__device__ __forceinline__ void wait_vm() {
    if constexpr (N == 0)      asm volatile("s_waitcnt vmcnt(0)" ::: "memory");
    else if constexpr (N == 8) asm volatile("s_waitcnt vmcnt(8)" ::: "memory");
}

// ---------------------------------------------------------------------------
// r4-verified GEMM task: 128x128 tile, BK=64, 4 waves (2x2, wave 64x64),
// 2-buf counted-vmcnt pipeline, both-sides XOR swizzle, swapped-operand MFMA
// (lane holds 4 consecutive C-cols of one slot row -> f32x4 epilogue).
// A: [kt][PADROWS][64] K-tiled; B: [(e*KT+kt)*NCOLS + col][64] K-tiled.
// All staging loads contiguous (r4 lever). No grid syncs inside.
// ---------------------------------------------------------------------------
template <int KDIM, int NCOLS, bool RELU, bool TILEOUT, typename TC>
__device__ void gemm_task(SMem* sm, int rt, int ct,
                          const __hip_bfloat16* __restrict__ A,
                          const __hip_bfloat16* __restrict__ B,
                          const float* __restrict__ bias,
                          const float* __restrict__ resid,
                          TC* __restrict__ C) {
    constexpr int BM  = 128;
    constexpr int BN  = 128;
    constexpr int BK  = 64;
    constexpr int KT  = KDIM / BK;
    constexpr int NJ  = 4;

    int cv[NEXP], off[NEXP + 1]; off[0] = 0;
#pragma unroll
    for (int q = 0; q < NEXP; ++q) { cv[q] = g_counts[q]; off[q + 1] = off[q] + ((cv[q] + 255) & ~255); }
    const int r0 = rt * BM;
    if (r0 >= off[NEXP]) return;                   // block-uniform, no syncs below
    int e = 0;
#pragma unroll
    for (int q = 0; q < NEXP - 1; ++q) if (r0 >= off[q + 1]) e = q + 1;

    const int tid  = threadIdx.x;
    const int wave = tid >> 6;
    const int lane = tid & 63;

    __syncthreads();                               // cross-task LDS reuse guard
    if (!TILEOUT) {
        if (tid < BM) {
            int ls = r0 + tid - off[e];
            sm->sTok[tid] = (ls < cv[e]) ? g_idx[e * N_TOK + ls] : -1;
        }
        __syncthreads();
    }

    const int srow = wave * 8 + (lane >> 3);           // row within 32-row chunk
    const int ssl  = ((lane & 7) ^ (lane >> 3)) * 8;   // swizzled source slot

    auto stage = [&](int buf, int kt) {
#pragma unroll
        for (int q = 0; q < 4; ++q)
            gl16(A + ((size_t)kt * PADROWS + r0 + q * 32 + srow) * 64 + ssl,
                 &sm->sA[buf][(q * 256 + wave * 64) * 8]);
#pragma unroll
        for (int q = 0; q < 4; ++q)
            gl16(B + ((size_t)(e * KT + kt) * NCOLS + ct * BN + q * 32 + srow) * 64 + ssl,
                 &sm->sB[buf][(q * 256 + wave * 64) * 8]);
    };

    const int wm   = (wave >> 1) * 64;
    const int wn   = (wave & 1) * 64;
    const int frow = lane & 15;
    int cof[2];
#pragma unroll
    for (int ks = 0; ks < 2; ++ks)
        cof[ks] = ((ks * 4 + (lane >> 4)) ^ (lane & 7)) * 8;

    f32x4 acc[4][NJ] = {};

    auto compute = [&](int buf) {
        const __hip_bfloat16* pA = &sm->sA[buf][0];
        const __hip_bfloat16* pB = &sm->sB[buf][0];
#pragma unroll
        for (int ks = 0; ks < 2; ++ks) {
            bf16x8 bfr[NJ];
#pragma unroll
            for (int j = 0; j < NJ; ++j)
                bfr[j] = *(const bf16x8*)&pB[(wn + j * 16 + frow) * BK + cof[ks]];
#pragma unroll
            for (int i = 0; i < 4; ++i) {
                bf16x8 af = *(const bf16x8*)&pA[(wm + i * 16 + frow) * BK + cof[ks]];
#pragma unroll
                for (int j = 0; j < NJ; ++j)       // SWAPPED operands
                    acc[i][j] = __builtin_amdgcn_mfma_f32_16x16x32_bf16(
                        bfr[j], af, acc[i][j], 0, 0, 0);
            }
        }
    };

    stage(0, 0);
    stage(1, 1);

    int cur = 0;
    for (int t = 0; t < KT - 1; ++t) {
        wait_vm<8>();                              // tile t done; t+1 in flight
        __builtin_amdgcn_s_barrier();
        __builtin_amdgcn_sched_barrier(0);
        compute(cur);
        asm volatile("" ::: "memory");
        __builtin_amdgcn_s_barrier();
        if (t + 2 < KT) stage(cur, t + 2);
        cur ^= 1;
    }
    wait_vm<0>();
    __builtin_amdgcn_s_barrier();
    __builtin_amdgcn_sched_barrier(0);
    compute(cur);

    // epilogue: slot row = r0+wm+i*16+(lane&15); col = ct*BN+wn+j*16+(lane>>4)*4+r
    const int lrow = lane & 15;
    const int lcol = (lane >> 4) * 4;
#pragma unroll
    for (int i = 0; i < 4; ++i) {
        const int rl = wm + i * 16 + lrow;
        const int gs = r0 + rl;
#pragma unroll
        for (int j = 0; j < NJ; ++j) {
            const int col = ct * BN + wn + j * 16 + lcol;
            const f32x4 bv = *(const f32x4*)&bias[(size_t)e * NCOLS + col];
            f32x4 v = acc[i][j] + bv;
            if (RELU) {
#pragma unroll
                for (int r = 0; r < 4; ++r) v[r] = fmaxf(v[r], 0.0f);
            }
            if constexpr (TILEOUT) {
                bf16x4 h;
                h[0] = (__bf16)v[0]; h[1] = (__bf16)v[1];
                h[2] = (__bf16)v[2]; h[3] = (__bf16)v[3];
                *(bf16x4*)&C[((size_t)(col >> 6) * PADROWS + gs) * 64 + (col & 63)] = h;
            } else {
                const int tk = sm->sTok[rl];
                if (tk >= 0) {
                    v += *(const f32x4*)&resid[(size_t)tk * NCOLS + col];
                    *(f32x4*)&C[(size_t)tk * NCOLS + col] = v;
                }
            }
        }
    }
}

// ---------------------------------------------------------------------------
// The fused persistent kernel: P0 {W-convert, per-block token counts} ->
// P1 {prefix scan, g_idx scatter, totals} -> P2 {Xp gather-convert} ->
// P3 {gemm1} -> P4 {gemm2}. Exactly 4 gsync() per block, unconditionally.
// ---------------------------------------------------------------------------
__global__ __launch_bounds__(NTHR, 2)
void fused_kernel(const float* __restrict__ x, const void* __restrict__ dom,
                  const float* __restrict__ w1, const float* __restrict__ b1,
                  const float* __restrict__ w2, const float* __restrict__ b2,
                  float* __restrict__ out) {
    __shared__ SMem sm;
    const int bid  = blockIdx.x;
    const int tid  = threadIdx.x;
    const int lane = tid & 63;

    // ---- P0a: W convert + re-tile (grid-stride) ----
    {
        constexpr int HALF = NEXP * MDIM * DDIM / 8;       // 524288
        for (int g = bid * NTHR + tid; g < 2 * HALF; g += NB * NTHR) {
            const bool is1 = (g < HALF);
            const int g8 = is1 ? g : g - HALF;
            const float* src = is1 ? w1 : w2;
            __hip_bfloat16* dst = is1 ? g_W1t : g_W2t;
            const int e   = g8 >> 17;                      // 131072 groups/expert
            const int rem = g8 & 131071;
            int row, kt, within;
            if (is1) { row = rem >> 8; int d0 = (rem & 255) * 8; kt = d0 >> 6; within = d0 & 63; }
            else     { row = rem >> 6; int m0 = (rem & 63) * 8;  kt = m0 >> 6; within = m0 & 63; }
            const float* s = src + (size_t)g8 * 8;
            f32x4 a = *(const f32x4*)s;
            f32x4 b = *(const f32x4*)(s + 4);
            bf16x8 r;
            r[0] = (__bf16)a[0]; r[1] = (__bf16)a[1]; r[2] = (__bf16)a[2]; r[3] = (__bf16)a[3];
            r[4] = (__bf16)b[0]; r[5] = (__bf16)b[1]; r[6] = (__bf16)b[2]; r[7] = (__bf16)b[3];
            const size_t d = is1 ? (((size_t)(e * 32 + kt) * MDIM + row) * 64 + within)
                                 : (((size_t)(e * 8 + kt) * DDIM + row) * 64 + within);
            *(bf16x8*)&dst[d] = r;
        }
    }
    // ---- P0b: per-block token counts (16 tokens/block, wave 0) ----
    if (tid < 64) {
        const long long* d64 = (const long long*)dom;
        long long probe = d64[lane];
        bool mode64 = (__ballot(probe >= 0 && probe < NEXP) == ~0ull);
        int e = -1;
        if (lane < 16) {
            int i = bid * 16 + lane;
            e = mode64 ? (int)d64[i] : ((const int*)dom)[i];
        }
#pragma unroll
        for (int ex = 0; ex < NEXP; ++ex) {
            unsigned long long m = __ballot(e == ex);
            if (lane == 0) g_blkcnt[bid][ex] = __popcll(m);
        }
    }
    gsync();   // ---- sync 1 ----

    // ---- P1: prefix scan over block counts (LDS overlay on sA) + scatter ----
    {
        int (*sc)[256] = reinterpret_cast<int(*)[256]>(&sm.sA[0][0]);
#pragma unroll
        for (int e2 = 0; e2 < NEXP; ++e2)
            sc[e2][tid] = g_blkcnt[2 * tid][e2] + g_blkcnt[2 * tid + 1][e2];
        __syncthreads();
        for (int o = 1; o < 256; o <<= 1) {
            int v[NEXP];
            if (tid >= o) {
#pragma unroll
                for (int e2 = 0; e2 < NEXP; ++e2) v[e2] = sc[e2][tid - o];
            }
            __syncthreads();
            if (tid >= o) {
#pragma unroll
                for (int e2 = 0; e2 < NEXP; ++e2) sc[e2][tid] += v[e2];
            }
            __syncthreads();
        }
        if (tid < 64) {
            const long long* d64 = (const long long*)dom;
            long long probe = d64[lane];
            bool mode64 = (__ballot(probe >= 0 && probe < NEXP) == ~0ull);
            int e = -1;
            if (lane < 16) {
                int i = bid * 16 + lane;
                e = mode64 ? (int)d64[i] : ((const int*)dom)[i];
            }
            const int q = bid >> 1;
#pragma unroll
            for (int ex = 0; ex < NEXP; ++ex) {
                unsigned long long m = __ballot(e == ex);
                if (e == ex) {
                    int base = (q > 0 ? sc[ex][q - 1] : 0)
                             + ((bid & 1) ? g_blkcnt[bid - 1][ex] : 0);
                    int pos = base + __popcll(m & ((1ull << lane) - 1ull));
                    g_idx[ex * N_TOK + pos] = bid * 16 + lane;
                }
            }
        }
        if (bid == 0 && tid < NEXP) g_counts[tid] = sc[tid][255];
    }
    gsync();   // ---- sync 2 ----

    // ---- P2: x gather-permute-convert -> g_Xp (18 rows/block) ----
    {
        int cv[NEXP], off[NEXP + 1]; off[0] = 0;
#pragma unroll
        for (int e2 = 0; e2 < NEXP; ++e2) { cv[e2] = g_counts[e2]; off[e2 + 1] = off[e2] + ((cv[e2] + 255) & ~255); }
        for (int ri = 0; ri < PADROWS / NB; ++ri) {
            const int gs = bid * (PADROWS / NB) + ri;
            int e = 0;
#pragma unroll
            for (int q = 0; q < NEXP - 1; ++q) if (gs >= off[q + 1]) e = q + 1;
            if (gs < off[e + 1]) {
                int ls = gs - off[e];
                if (ls >= cv[e]) ls = cv[e] - 1;
                if (ls < 0) ls = 0;
                const int tok = g_idx[e * N_TOK + ls];
                const int d0 = tid * 8;
                const float* s = x + (size_t)tok * DDIM + d0;
                f32x4 a = *(const f32x4*)s;
                f32x4 b = *(const f32x4*)(s + 4);
                bf16x8 r;
                r[0] = (__bf16)a[0]; r[1] = (__bf16)a[1]; r[2] = (__bf16)a[2]; r[3] = (__bf16)a[3];
                r[4] = (__bf16)b[0]; r[5] = (__bf16)b[1]; r[6] = (__bf16)b[2]; r[7] = (__bf16)b[3];
                *(bf16x8*)&g_Xp[((size_t)(d0 >> 6) * PADROWS + gs) * 64 + (d0 & 63)] = r;
            }
        }
    }
    gsync();   // ---- sync 3 ----

    // ---- P3: gemm1  Hp = relu(Xp @ W1t[e]^T + b1)  [K=2048, cols=512] ----
    // 288 static tasks (72 rt x 4 ct); XCD ct-striping: s=(t&7)*36+(t>>3).
    for (int t = bid; t < 288; t += NB) {
        const int s = (t & 7) * 36 + (t >> 3);
        gemm_task<DDIM, MDIM, true, true, __hip_bfloat16>(
            &sm, s % 72, s / 72, g_Xp, g_W1t, b1, nullptr, g_Hp);
    }
    gsync();   // ---- sync 4 ----

    // ---- P4: gemm2  out = x + Hp @ W2t[e]^T + b2  [K=512, cols=2048] ----
    // 1152 static tasks (72 rt x 16 ct); s=(t&7)*144+(t>>3); +NB keeps (t&7).
    for (int t = bid; t < 1152; t += NB) {
        const int s = (t & 7) * 144 + (t >> 3);
        gemm_task<MDIM, DDIM, false, false, float>(
            &sm, s % 72, s / 72, g_Hp, g_W2t, b2, x, out);
    }
}

extern "C" void kernel_launch(void* const* d_in, const int* in_sizes, int n_in,
                              void* d_out, int out_size, void* d_ws, size_t ws_size,
                              hipStream_t stream) {
    const float* x  = (const float*)d_in[0];
    const void*  dm = d_in[1];
    const float* W1 = (const float*)d_in[2];
    const float* b1 = (const float*)d_in[3];
    const float* W2 = (const float*)d_in[4];
    const float* b2 = (const float*)d_in[5];
    float* out = (float*)d_out;

    fused_kernel<<<NB, NTHR, 0, stream>>>(x, dm, W1, b1, W2, b2, out);
}

// Round 7
// 240.312 us; speedup vs baseline: 1.7905x; 1.7905x over previous
//
#include <hip/hip_runtime.h>
#include <hip/hip_bf16.h>
#include <cstdint>
#include <type_traits>

// Problem constants (reference: N=8192, D=2048, M=512, E=4, SCALE=1)
#define N_TOK 8192
#define DDIM  2048
#define MDIM  512
#define NEXP  4
#define PADROWS (N_TOK + NEXP * 256)   // expert ranges padded to 256 -> 9216

typedef __bf16 bf16x4 __attribute__((ext_vector_type(4)));
typedef __bf16 bf16x8 __attribute__((ext_vector_type(8)));
typedef float  f32x4  __attribute__((ext_vector_type(4)));

// ---------------------------------------------------------------------------
// Scratch (module device globals, fully rewritten every call).
// K-tiled layouts (r4-proven): staging chunks are contiguous 4KB blocks so
// every global_load_lds is a contiguous 1KB-per-wave burst.
// ---------------------------------------------------------------------------
__device__ int g_counts[NEXP];
__device__ int g_idx[NEXP * N_TOK];
__device__ __align__(16) __hip_bfloat16 g_Xp[(size_t)DDIM * PADROWS];       // 37.7 MB
__device__ __align__(16) __hip_bfloat16 g_Hp[(size_t)MDIM * PADROWS];       //  9.4 MB
__device__ __align__(16) __hip_bfloat16 g_W1t[(size_t)NEXP * MDIM * DDIM];  //  8.4 MB
__device__ __align__(16) __hip_bfloat16 g_W2t[(size_t)NEXP * DDIM * MDIM];  //  8.4 MB

// ---------------------------------------------------------------------------
// Single-block deterministic bucketing: count + block-scan + scatter.
// Replaces zero_counts + atomic bucket (2 launches -> 1, no atomics).
// 1024 threads x 8 tokens each; Hillis-Steele inclusive scan in LDS.
// ---------------------------------------------------------------------------
__global__ __launch_bounds__(1024)
void bucket1_kernel(const void* __restrict__ domv) {
    __shared__ int sc[NEXP][1024];
    const int tid  = threadIdx.x;
    const int lane = tid & 63;

    // dtype detect (verified r1-r6): all of the first 64 int64-views in range
    const long long* d64 = (const long long*)domv;
    long long probe = d64[lane];
    bool mode64 = (__ballot(probe >= 0 && probe < NEXP) == ~0ull);

    int e[8];
    int cnt[NEXP] = {};
#pragma unroll
    for (int k = 0; k < 8; ++k) {
        const int i = tid * 8 + k;
        e[k] = mode64 ? (int)d64[i] : ((const int*)domv)[i];
#pragma unroll
        for (int x = 0; x < NEXP; ++x) cnt[x] += (e[k] == x);   // static idx
    }
#pragma unroll
    for (int x = 0; x < NEXP; ++x) sc[x][tid] = cnt[x];
    __syncthreads();

    for (int o = 1; o < 1024; o <<= 1) {
        int v[NEXP];
        if (tid >= o) {
#pragma unroll
            for (int x = 0; x < NEXP; ++x) v[x] = sc[x][tid - o];
        }
        __syncthreads();
        if (tid >= o) {
#pragma unroll
            for (int x = 0; x < NEXP; ++x) sc[x][tid] += v[x];
        }
        __syncthreads();
    }

    int base[NEXP];
#pragma unroll
    for (int x = 0; x < NEXP; ++x) base[x] = sc[x][tid] - cnt[x];  // exclusive
#pragma unroll
    for (int k = 0; k < 8; ++k) {
#pragma unroll
        for (int x = 0; x < NEXP; ++x) {                 // static-indexed write
            if (e[k] == x) g_idx[x * N_TOK + base[x]] = tid * 8 + k;
            base[x] += (e[k] == x);
        }
    }
    if (tid < NEXP) g_counts[tid] = sc[tid][1023];
}

// ---------------------------------------------------------------------------
// Combined convert pass (ONE launch, merges r4's cvt_w + cvt_xp):
//  y=0: x gather-permute-convert -> g_Xp [kt64][slot][64], expert-sorted slots
//  y=1: W1 -> g_W1t [(e*32+kt)*512+m][64]; W2 -> g_W2t [(e*8+kt)*2048+d][64]
// ---------------------------------------------------------------------------
__global__ __launch_bounds__(256)
void cvt_all_kernel(const float* __restrict__ x,
                    const float* __restrict__ w1,
                    const float* __restrict__ w2) {
    if (blockIdx.y == 0) {
        int c[NEXP], off[NEXP + 1]; off[0] = 0;
#pragma unroll
        for (int e = 0; e < NEXP; ++e) { c[e] = g_counts[e]; off[e + 1] = off[e] + ((c[e] + 255) & ~255); }
        const int gs = blockIdx.x;
        int e = 0;
#pragma unroll
        for (int t = 0; t < NEXP - 1; ++t) if (gs >= off[t + 1]) e = t + 1;
        if (gs >= off[e + 1]) return;
        int ls = gs - off[e];
        if (ls >= c[e]) ls = c[e] - 1;
        if (ls < 0) ls = 0;
        const int tok = g_idx[e * N_TOK + ls];

        const int d0 = threadIdx.x * 8;
        const float* s = x + (size_t)tok * DDIM + d0;
        f32x4 a = *(const f32x4*)s;
        f32x4 b = *(const f32x4*)(s + 4);
        bf16x8 r;
        r[0] = (__bf16)a[0]; r[1] = (__bf16)a[1]; r[2] = (__bf16)a[2]; r[3] = (__bf16)a[3];
        r[4] = (__bf16)b[0]; r[5] = (__bf16)b[1]; r[6] = (__bf16)b[2]; r[7] = (__bf16)b[3];
        *(bf16x8*)&g_Xp[((size_t)(d0 >> 6) * PADROWS + gs) * 64 + (d0 & 63)] = r;
    } else {
        constexpr int HALF = NEXP * MDIM * DDIM / 8;       // 524288 groups
        const int gtid = blockIdx.x * 256 + threadIdx.x;
        if (gtid >= 2 * HALF) return;
        const bool is1 = (gtid < HALF);
        const int g8 = is1 ? gtid : gtid - HALF;
        const float* src = is1 ? w1 : w2;
        __hip_bfloat16* dst = is1 ? g_W1t : g_W2t;

        const int e   = g8 >> 17;                          // 131072 groups/expert
        const int rem = g8 & 131071;
        int row, kt, within;
        if (is1) { row = rem >> 8; int d0 = (rem & 255) * 8; kt = d0 >> 6; within = d0 & 63; }
        else     { row = rem >> 6; int m0 = (rem & 63) * 8;  kt = m0 >> 6; within = m0 & 63; }
        const float* s = src + (size_t)g8 * 8;
        f32x4 a = *(const f32x4*)s;
        f32x4 b = *(const f32x4*)(s + 4);
        bf16x8 r;
        r[0] = (__bf16)a[0]; r[1] = (__bf16)a[1]; r[2] = (__bf16)a[2]; r[3] = (__bf16)a[3];
        r[4] = (__bf16)b[0]; r[5] = (__bf16)b[1]; r[6] = (__bf16)b[2]; r[7] = (__bf16)b[3];
        const size_t d = is1 ? (((size_t)(e * 32 + kt) * MDIM + row) * 64 + within)
                             : (((size_t)(e * 8 + kt) * DDIM + row) * 64 + within);
        *(bf16x8*)&dst[d] = r;
    }
}

// ---------------------------------------------------------------------------
// global -> LDS direct DMA, 16B/lane (wave-uniform LDS base + lane*16).
// ---------------------------------------------------------------------------
__device__ __forceinline__ void gl16(const __hip_bfloat16* g, __hip_bfloat16* l) {
    __builtin_amdgcn_global_load_lds(
        (const __attribute__((address_space(1))) void*)g,
        (__attribute__((address_space(3))) void*)l,
        16, 0, 0);
}

// counted vmcnt (T4): literal immediates via constexpr dispatch
template <int N>
__device__ __forceinline__ void wait_vm() {
    if constexpr (N == 0)      asm volatile("s_waitcnt vmcnt(0)" ::: "memory");
    else if constexpr (N == 8) asm volatile("s_waitcnt vmcnt(8)" ::: "memory");
}

// ---------------------------------------------------------------------------
// r4-VERBATIM GEMM engine: 128x128 tile, BK=64, 256 thr = 4 waves (2x2, wave
// 64x64), 2-buf counted-vmcnt pipeline, both-sides XOR swizzle, swapped-
// operand MFMA (lane holds 4 consecutive C-cols of one slot row -> f32x4
// epilogue). A: [kt][PADROWS][64]; B: [(e*KT+kt)*NCOLS+col][64]. All staging
// contiguous (the r4 lever). Measured r4: 47us, MfmaUtil 13.5%, 0 conflicts.
// Round-7 change: gemm1 now uses BN=128 too (was 64) -> A-restage halves
// (302->151 MB), geometry identical to the proven gemm2 config.
// ---------------------------------------------------------------------------
template <int BN, int KDIM, int NCOLS, bool RELU, bool TILEOUT, typename TC>
__device__ __forceinline__ void gemm_core(const __hip_bfloat16* __restrict__ A,
                                          const __hip_bfloat16* __restrict__ B,
                                          const float* __restrict__ bias,
                                          const float* __restrict__ resid,
                                          TC* __restrict__ C) {
    constexpr int BM    = 128;
    constexpr int BK    = 64;
    constexpr int KT    = KDIM / BK;
    constexpr int NACH  = 4;
    constexpr int NBCH  = BN / 32;
    constexpr int LPS   = NACH + NBCH;
    constexpr int NJ    = BN / 32;
    constexpr int NSTEP = KT;

    const int rt = blockIdx.x;
    const int ct = blockIdx.y;

    int cv[NEXP], off[NEXP + 1]; off[0] = 0;
#pragma unroll
    for (int x = 0; x < NEXP; ++x) { cv[x] = g_counts[x]; off[x + 1] = off[x] + ((cv[x] + 255) & ~255); }
    const int r0 = rt * BM;
    if (r0 >= off[NEXP]) return;        // uniform
    int e = 0;
#pragma unroll
    for (int t = 0; t < NEXP - 1; ++t) if (r0 >= off[t + 1]) e = t + 1;

    __shared__ __align__(16) __hip_bfloat16 sA[2][BM * BK];
    __shared__ __align__(16) __hip_bfloat16 sB[2][BN * BK];
    __shared__ int sTok[BM];

    const int tid  = threadIdx.x;
    const int wave = tid >> 6;
    const int lane = tid & 63;

    if (!TILEOUT) {                     // token map needed only for epilogue
        if (tid < BM) {
            int ls = r0 + tid - off[e];
            sTok[tid] = (ls < cv[e]) ? g_idx[e * N_TOK + ls] : -1;
        }
        __syncthreads();
    }

    const int srow = wave * 8 + (lane >> 3);          // row within 32-row chunk
    const int ssl  = ((lane & 7) ^ (lane >> 3)) * 8;  // swizzled source slot

    auto stage = [&](int buf, int kt) {
#pragma unroll
        for (int q = 0; q < NACH; ++q)
            gl16(A + ((size_t)kt * PADROWS + r0 + q * 32 + srow) * 64 + ssl,
                 &sA[buf][(q * 256 + wave * 64) * 8]);
#pragma unroll
        for (int q = 0; q < NBCH; ++q)
            gl16(B + ((size_t)(e * KT + kt) * NCOLS + ct * BN + q * 32 + srow) * 64 + ssl,
                 &sB[buf][(q * 256 + wave * 64) * 8]);
    };

    const int wm   = (wave >> 1) * 64;
    const int wn   = (wave & 1) * (BN / 2);
    const int frow = lane & 15;
    int cof[2];
#pragma unroll
    for (int ks = 0; ks < 2; ++ks)
        cof[ks] = ((ks * 4 + (lane >> 4)) ^ (lane & 7)) * 8;

    f32x4 acc[4][NJ] = {};

    auto compute = [&](int buf) {
        const __hip_bfloat16* pA = &sA[buf][0];
        const __hip_bfloat16* pB = &sB[buf][0];
#pragma unroll
        for (int ks = 0; ks < 2; ++ks) {
            bf16x8 bfr[NJ];
#pragma unroll
            for (int j = 0; j < NJ; ++j)
                bfr[j] = *(const bf16x8*)&pB[(wn + j * 16 + frow) * BK + cof[ks]];
#pragma unroll
            for (int i = 0; i < 4; ++i) {
                bf16x8 af = *(const bf16x8*)&pA[(wm + i * 16 + frow) * BK + cof[ks]];
#pragma unroll
                for (int j = 0; j < NJ; ++j)       // SWAPPED operands
                    acc[i][j] = __builtin_amdgcn_mfma_f32_16x16x32_bf16(
                        bfr[j], af, acc[i][j], 0, 0, 0);
            }
        }
    };

    stage(0, 0);
    stage(1, 1);

    int cur = 0;
    for (int t = 0; t < NSTEP - 1; ++t) {
        wait_vm<LPS>();                 // tile t done; t+1 stays in flight
        __builtin_amdgcn_s_barrier();
        __builtin_amdgcn_sched_barrier(0);
        compute(cur);
        asm volatile("" ::: "memory");
        __builtin_amdgcn_s_barrier();
        if (t + 2 < NSTEP) stage(cur, t + 2);
        cur ^= 1;
    }
    wait_vm<0>();
    __builtin_amdgcn_s_barrier();
    __builtin_amdgcn_sched_barrier(0);
    compute(cur);

    // epilogue: slot row = r0+wm+i*16+(lane&15); col = ct*BN+wn+j*16+(lane>>4)*4+r
    const int lrow = lane & 15;
    const int lcol = (lane >> 4) * 4;
#pragma unroll
    for (int i = 0; i < 4; ++i) {
        const int rl = wm + i * 16 + lrow;
        const int gs = r0 + rl;
#pragma unroll
        for (int j = 0; j < NJ; ++j) {
            const int col = ct * BN + wn + j * 16 + lcol;
            const f32x4 bv = *(const f32x4*)&bias[(size_t)e * NCOLS + col];
            f32x4 v = acc[i][j] + bv;
            if (RELU) {
#pragma unroll
                for (int r = 0; r < 4; ++r) v[r] = fmaxf(v[r], 0.0f);
            }
            if constexpr (TILEOUT) {
                bf16x4 h;
                h[0] = (__bf16)v[0]; h[1] = (__bf16)v[1];
                h[2] = (__bf16)v[2]; h[3] = (__bf16)v[3];
                *(bf16x4*)&C[((size_t)(col >> 6) * PADROWS + gs) * 64 + (col & 63)] = h;
            } else {
                const int tk = sTok[rl];
                if (tk >= 0) {
                    v += *(const f32x4*)&resid[(size_t)tk * NCOLS + col];
                    *(f32x4*)&C[(size_t)tk * NCOLS + col] = v;
                }
            }
        }
    }
}

// GEMM1: Hp = relu(Xp @ W1t[e]^T + b1)  [K=2048, cols=512]
// Now 128x128 (r7): A-restage 151MB (was 302), LDS 64.5KB -> 2/CU, grid (72,4).
__global__ __launch_bounds__(256)
void gemm1_kernel(const float* __restrict__ b1) {
    gemm_core<128, DDIM, MDIM, true, true, __hip_bfloat16>(
        g_Xp, g_W1t, b1, nullptr, g_Hp);
}

// GEMM2: out = x + Hp @ W2t[e]^T + b2  [K=512, cols=2048]  (r4 verbatim, 47us)
__global__ __launch_bounds__(256)
void gemm2_kernel(const float* __restrict__ x,
                  const float* __restrict__ b2,
                  float* __restrict__ out) {
    gemm_core<128, MDIM, DDIM, false, false, float>(
        g_Hp, g_W2t, b2, x, out);
}

extern "C" void kernel_launch(void* const* d_in, const int* in_sizes, int n_in,
                              void* d_out, int out_size, void* d_ws, size_t ws_size,
                              hipStream_t stream) {
    const float* x  = (const float*)d_in[0];
    const void*  dm = d_in[1];
    const float* W1 = (const float*)d_in[2];
    const float* b1 = (const float*)d_in[3];
    const float* W2 = (const float*)d_in[4];
    const float* b2 = (const float*)d_in[5];
    float* out = (float*)d_out;

    bucket1_kernel<<<1, 1024, 0, stream>>>(dm);
    cvt_all_kernel<<<dim3(PADROWS, 2), 256, 0, stream>>>(x, W1, W2);
    gemm1_kernel<<<dim3(PADROWS / 128, MDIM / 128), 256, 0, stream>>>(b1);
    gemm2_kernel<<<dim3(PADROWS / 128, DDIM / 128), 256, 0, stream>>>(x, b2, out);
}